// Round 13
// baseline (521.486 us; speedup 1.0000x reference)
//
#include <hip/hip_runtime.h>
#include <hip/hip_fp16.h>
#include <math.h>

#define NN 50000
#define NE 800000
#define NG 512
#define NET (NE + NN)            // edges + self loops
#define NCH ((NN + 511) / 512)   // 98 scan chunks per branch
#define NT2 ((2 * NN + 63) / 64) // 1563 64-node tiles over both branches
#define GN4 ((2 * NN + 3) / 4)   // wave-per-node grids, both branches
#define XS 68                    // node-major LDS stride (x4B: 2-way banks max)
#define PART 6250                // NN / 8 — dst slice per XCD

typedef unsigned short u16;

__device__ __forceinline__ float wsum64(float v) {
#pragma unroll
    for (int o = 32; o > 0; o >>= 1) v += __shfl_down(v, o, 64);
    return v;
}

__device__ __forceinline__ float fast_tanh(float x) {
    return 1.f - 2.f / (__expf(2.f * x) + 1.f);
}

// ---------------- CSR build (both branches) ----------------

__global__ void k_deg(const int* __restrict__ eia, const int* __restrict__ eib,
                      int* __restrict__ cnt2) {
    int e = blockIdx.x * 256 + threadIdx.x;
    if (e >= 2 * NET) return;
    int br = e >= NET;
    int el = e - br * NET;
    const int* ei = br ? eib : eia;
    // nt load: edge stream must not evict cnt2 lines from L2
    int d = (el < NE) ? __builtin_nontemporal_load(&ei[NE + el]) : (el - NE);
    atomicAdd(&cnt2[br * NN + d], 1);
}

__global__ void k_scan1(const int* __restrict__ cnt2, int* __restrict__ partial) {
    int b = blockIdx.x;
    int br = b >= NCH, c = b - (br ? NCH : 0);
    int i = c * 512 + threadIdx.x;
    int v = (i < NN) ? cnt2[br * NN + i] : 0;
    __shared__ int sp[8];
    int lane = threadIdx.x & 63, w = threadIdx.x >> 6;
#pragma unroll
    for (int o = 32; o > 0; o >>= 1) v += __shfl_down(v, o, 64);
    if (lane == 0) sp[w] = v;
    __syncthreads();
    if (threadIdx.x == 0) {
        int s = 0;
#pragma unroll
        for (int k = 0; k < 8; k++) s += sp[k];
        partial[b] = s;
    }
}

__global__ void k_scan2(int* __restrict__ partial, int* __restrict__ rowptr2,
                        float* __restrict__ pool) {
    __shared__ int s[2 * NCH];
    int t = threadIdx.x;  // 256
    for (int i = t; i < 4 * NG; i += 256) pool[i] = 0.f;
    for (int i = t; i < 2 * NCH; i += 256) s[i] = partial[i];
    __syncthreads();
    if (t < 2) {
        int run = 0;
        for (int i = 0; i < NCH; i++) { int v = s[t * NCH + i]; s[t * NCH + i] = run; run += v; }
        rowptr2[t * (NN + 1) + NN] = run;
    }
    __syncthreads();
    for (int i = t; i < 2 * NCH; i += 256) partial[i] = s[i];
}

__global__ void k_scan3(const int* __restrict__ cnt2, const int* __restrict__ partial,
                        int* __restrict__ rowptr2, int* __restrict__ cursor2,
                        float* __restrict__ dinv2) {
    __shared__ int s[512];
    int b = blockIdx.x;
    int br = b >= NCH, c = b - (br ? NCH : 0);
    int t = threadIdx.x;
    int i = c * 512 + t;
    int v = (i < NN) ? cnt2[br * NN + i] : 0;
    s[t] = v;
    __syncthreads();
    for (int o = 1; o < 512; o <<= 1) {
        int add = (t >= o) ? s[t - o] : 0;
        __syncthreads();
        s[t] += add;
        __syncthreads();
    }
    if (i < NN) {
        int excl = s[t] - v + partial[b];
        rowptr2[br * (NN + 1) + i] = excl;
        cursor2[br * NN + i] = excl;
        dinv2[br * NN + i] = v > 0 ? rsqrtf((float)v) : 0.f;
    }
}

// XCD-partitioned scatter (round 9) + non-temporal edge stream (round 12):
// slice p's 425 KB csr2 region stays resident in XCD p's L2 (the 6.8 MB dst
// sweep no longer evicts it), so each line fills fully and writes back once.
__global__ __launch_bounds__(256) void k_scatter(
        const int* __restrict__ eia, const int* __restrict__ eib,
        int* __restrict__ cursor2, u16* __restrict__ csr2) {
    int p = blockIdx.x & 7;
    int blk = blockIdx.x >> 3;
    int nblk = gridDim.x >> 3;
    int lo = p * PART, hi = lo + PART;
    for (int e = blk * 256 + threadIdx.x; e < 2 * NET; e += nblk * 256) {
        int br = e >= NET;
        int el = e - br * NET;
        const int* ei = br ? eib : eia;
        int d = (el < NE) ? __builtin_nontemporal_load(&ei[NE + el]) : (el - NE);
        if (d >= lo && d < hi) {
            int s = (el < NE) ? __builtin_nontemporal_load(&ei[el]) : d;
            int pos = atomicAdd(&cursor2[br * NN + d], 1);
            csr2[br * NET + pos] = (u16)s;
        }
    }
}

// ---------------- node-level kernels (node id in [0,2*NN)) ----

__global__ void k_gat_input(const float* __restrict__ xa, const float* __restrict__ xb,
                            const float* __restrict__ Wg,
                            const float* __restrict__ avs, const float* __restrict__ avd,
                            __half* __restrict__ A, float* __restrict__ als,
                            float* __restrict__ ald) {
    __shared__ float sW[9 * 64];
    __shared__ float sas[64], sad[64];
    int t = threadIdx.x;
    for (int i = t; i < 9 * 64; i += 256) sW[i] = Wg[i];
    if (t < 64) { sas[t] = avs[t]; sad[t] = avd[t]; }
    __syncthreads();
    int n = blockIdx.x * 4 + (t >> 6);
    int u = t & 63;
    if (n >= 2 * NN) return;
    const float* xp = (n < NN) ? &xa[(size_t)n * 9] : &xb[(size_t)(n - NN) * 9];
    float h = 0.f;
#pragma unroll
    for (int f = 0; f < 9; f++) h += xp[f] * sW[f * 64 + u];
    A[(size_t)n * 64 + u] = __float2half(h);
    float ps = wsum64(h * sas[u]);
    float pd = wsum64(h * sad[u]);
    if (u == 0) { als[n] = ps; ald[n] = pd; }
}

// GAT two-phase: per 64-edge chunk, phase A computes edge weights lane-parallel
// (coalesced index load, ONE exp per edge instead of 64), phase B shfl-broadcasts
// (s_j, w_j) and does the feature-parallel gather-FMA. No max-stab (|e|<~25).
__global__ __launch_bounds__(256) void k_gat_csr(
        const int* __restrict__ rowptr2, const u16* __restrict__ csr2,
        const float* __restrict__ als, const float* __restrict__ ald,
        const __half* __restrict__ A, const float* __restrict__ bias,
        __half* __restrict__ B) {
    int dg = blockIdx.x * 4 + (threadIdx.x >> 6);
    int u = threadIdx.x & 63;
    if (dg >= 2 * NN) return;
    int br = dg >= NN;
    int d = dg - br * NN;
    const int* rp = rowptr2 + br * (NN + 1);
    const u16* cs = csr2 + br * NET;
    int nb = br * NN;
    int beg = rp[d], end = rp[d + 1];
    float ad = ald[dg];
    float acc = 0.f;
    float denl = 0.f;
    for (int c = beg; c < end; c += 64) {
        int idx = c + u;
        int s = 0;
        float w = 0.f;
        if (idx < end) {
            s = nb + cs[idx];
            float v = als[s] + ad;
            w = __expf(fmaxf(v, 0.2f * v));
        }
        denl += w;
        int m = end - c; if (m > 64) m = 64;
        int j = 0;
        for (; j + 4 <= m; j += 4) {
            int s0 = __shfl(s, j, 64),     s1 = __shfl(s, j + 1, 64);
            int s2 = __shfl(s, j + 2, 64), s3 = __shfl(s, j + 3, 64);
            float w0 = __shfl(w, j, 64),     w1 = __shfl(w, j + 1, 64);
            float w2 = __shfl(w, j + 2, 64), w3 = __shfl(w, j + 3, 64);
            float f0 = __half2float(A[(size_t)s0 * 64 + u]);
            float f1 = __half2float(A[(size_t)s1 * 64 + u]);
            float f2 = __half2float(A[(size_t)s2 * 64 + u]);
            float f3 = __half2float(A[(size_t)s3 * 64 + u]);
            acc += f0 * w0 + f1 * w1 + f2 * w2 + f3 * w3;
        }
        for (; j < m; j++) {
            int sj = __shfl(s, j, 64);
            float wj = __shfl(w, j, 64);
            acc += __half2float(A[(size_t)sj * 64 + u]) * wj;
        }
    }
    float den = wsum64(denl);
    den = __shfl(den, 0, 64);
    B[(size_t)dg * 64 + u] = __float2half(fast_tanh(acc / den + bias[u]));
}

// Stage 64-node fp16 tile into LDS node-major: sX[node * XS + feat].
__device__ __forceinline__ void load_tile_NM(const __half* __restrict__ X, int base,
                                             float* sX, int t) {
    const __half2* X2 = (const __half2*)X;
    for (int i = t; i < 2048; i += 256) {
        int node = i >> 5, p = i & 31;
        float2 v;
        if (base + node < 2 * NN) v = __half22float2(X2[(size_t)(base + node) * 32 + p]);
        else v = make_float2(0.f, 0.f);
        *(float2*)&sX[node * XS + 2 * p] = v;
    }
}

// Dense Y = dinv[n] * (X @ W), 64-node tile, 4x4 blocking, fp16 weights/IO.
__global__ __launch_bounds__(256) void k_lin_tile(
        const __half* __restrict__ X, const float* __restrict__ W,
        const float* __restrict__ dinv, __half* __restrict__ Y) {
    __shared__ __half sW[64 * 64];
    __shared__ float sX[64 * XS];
    int t = threadIdx.x;
    for (int i = t; i < 4096; i += 256) sW[i] = __float2half(W[i]);
    int base = blockIdx.x * 64;
    load_tile_NM(X, base, sX, t);
    __syncthreads();
    int tx = t & 15, ty = t >> 4;
    float acc[4][4];
#pragma unroll
    for (int i = 0; i < 4; i++)
#pragma unroll
        for (int j = 0; j < 4; j++) acc[i][j] = 0.f;
#pragma unroll 4
    for (int k = 0; k < 64; k++) {
        const __half2* wp = (const __half2*)&sW[k * 64 + 4 * tx];
        float2 wa = __half22float2(wp[0]);
        float2 wb = __half22float2(wp[1]);
        float x0 = sX[(4 * ty + 0) * XS + k];
        float x1 = sX[(4 * ty + 1) * XS + k];
        float x2 = sX[(4 * ty + 2) * XS + k];
        float x3 = sX[(4 * ty + 3) * XS + k];
        acc[0][0] += x0 * wa.x; acc[0][1] += x0 * wa.y; acc[0][2] += x0 * wb.x; acc[0][3] += x0 * wb.y;
        acc[1][0] += x1 * wa.x; acc[1][1] += x1 * wa.y; acc[1][2] += x1 * wb.x; acc[1][3] += x1 * wb.y;
        acc[2][0] += x2 * wa.x; acc[2][1] += x2 * wa.y; acc[2][2] += x2 * wb.x; acc[2][3] += x2 * wb.y;
        acc[3][0] += x3 * wa.x; acc[3][1] += x3 * wa.y; acc[3][2] += x3 * wb.x; acc[3][3] += x3 * wb.y;
    }
#pragma unroll
    for (int i = 0; i < 4; i++) {
        int n = base + 4 * ty + i;
        if (n < 2 * NN) {
            float dv = dinv[n];
            __half2* Y2 = (__half2*)&Y[(size_t)n * 64 + 4 * tx];
            Y2[0] = __floats2half2_rn(acc[i][0] * dv, acc[i][1] * dv);
            Y2[1] = __floats2half2_rn(acc[i][2] * dv, acc[i][3] * dv);
        }
    }
}

// Lean GCN gather on pre-scaled Y: out = tanh(dinv_d * sum Y[s] + b).
__global__ __launch_bounds__(256) void k_gcn_gather(
        const int* __restrict__ rowptr2, const u16* __restrict__ csr2,
        const float* __restrict__ dinv, const __half* __restrict__ Y,
        const float* __restrict__ bias, __half* __restrict__ Bout) {
    int dg = blockIdx.x * 4 + (threadIdx.x >> 6);
    int u = threadIdx.x & 63;
    if (dg >= 2 * NN) return;
    int br = dg >= NN;
    int d = dg - br * NN;
    const int* rp = rowptr2 + br * (NN + 1);
    const u16* cs = csr2 + br * NET;
    int nb = br * NN;
    int beg = rp[d], end = rp[d + 1];
    float a0 = 0.f, a1 = 0.f, a2 = 0.f, a3 = 0.f;
    for (int c = beg; c < end; c += 64) {
        int idx = c + u;
        int s = (idx < end) ? nb + cs[idx] : 0;   // coalesced
        int m = end - c; if (m > 64) m = 64;
        int j = 0;
        for (; j + 4 <= m; j += 4) {
            int s0 = __shfl(s, j, 64),     s1 = __shfl(s, j + 1, 64);
            int s2 = __shfl(s, j + 2, 64), s3 = __shfl(s, j + 3, 64);
            a0 += __half2float(Y[(size_t)s0 * 64 + u]);
            a1 += __half2float(Y[(size_t)s1 * 64 + u]);
            a2 += __half2float(Y[(size_t)s2 * 64 + u]);
            a3 += __half2float(Y[(size_t)s3 * 64 + u]);
        }
        for (; j < m; j++) {
            int sj = __shfl(s, j, 64);
            a0 += __half2float(Y[(size_t)sj * 64 + u]);
        }
    }
    float h = ((a0 + a1) + (a2 + a3)) * dinv[dg];
    Bout[(size_t)dg * 64 + u] = __float2half(fast_tanh(h + bias[u]));
}

// MLP (64->64 tanh ->32 tanh ->1) + mean-pool. Node-major LDS, fp16 weights,
// segmented-run pool atomics.
__global__ __launch_bounds__(256) void k_mlp_pool(
        const __half* __restrict__ X,
        const int* __restrict__ batch_a, const int* __restrict__ batch_b,
        const float* __restrict__ W1, const float* __restrict__ b1,
        const float* __restrict__ W2, const float* __restrict__ b2,
        const float* __restrict__ W3, const float* __restrict__ b3,
        float* __restrict__ pool) {
    __shared__ __half sW1[64 * 64];
    __shared__ __half sW2[64 * 32];
    __shared__ float sX[64 * XS];
    __shared__ float sP[64 * 9];
    __shared__ float sW3[32], sb1[64], sb2[32];
    __shared__ int sKey[64];
    __shared__ float sVal[64];
    int t = threadIdx.x;
    for (int i = t; i < 4096; i += 256) sW1[i] = __float2half(W1[i]);
    for (int i = t; i < 2048; i += 256) sW2[i] = __float2half(W2[i]);
    if (t < 64) sb1[t] = b1[t];
    if (t < 32) { sW3[t] = W3[t]; sb2[t] = b2[t]; }
    float bb3 = b3[0];
    int base = blockIdx.x * 64;
    load_tile_NM(X, base, sX, t);
    __syncthreads();
    int tx = t & 15, ty = t >> 4;
    float acc[4][4];
#pragma unroll
    for (int i = 0; i < 4; i++)
#pragma unroll
        for (int j = 0; j < 4; j++) acc[i][j] = sb1[4 * tx + j];
#pragma unroll 4
    for (int k = 0; k < 64; k++) {
        const __half2* wp = (const __half2*)&sW1[k * 64 + 4 * tx];
        float2 wa = __half22float2(wp[0]);
        float2 wb = __half22float2(wp[1]);
        float x0 = sX[(4 * ty + 0) * XS + k];
        float x1 = sX[(4 * ty + 1) * XS + k];
        float x2 = sX[(4 * ty + 2) * XS + k];
        float x3 = sX[(4 * ty + 3) * XS + k];
        acc[0][0] += x0 * wa.x; acc[0][1] += x0 * wa.y; acc[0][2] += x0 * wb.x; acc[0][3] += x0 * wb.y;
        acc[1][0] += x1 * wa.x; acc[1][1] += x1 * wa.y; acc[1][2] += x1 * wb.x; acc[1][3] += x1 * wb.y;
        acc[2][0] += x2 * wa.x; acc[2][1] += x2 * wa.y; acc[2][2] += x2 * wb.x; acc[2][3] += x2 * wb.y;
        acc[3][0] += x3 * wa.x; acc[3][1] += x3 * wa.y; acc[3][2] += x3 * wb.x; acc[3][3] += x3 * wb.y;
    }
    __syncthreads();
#pragma unroll
    for (int i = 0; i < 4; i++) {
        float4 o = make_float4(fast_tanh(acc[i][0]), fast_tanh(acc[i][1]),
                               fast_tanh(acc[i][2]), fast_tanh(acc[i][3]));
        *(float4*)&sX[(4 * ty + i) * XS + 4 * tx] = o;
    }
    __syncthreads();
    int tx2 = t & 7, ty2 = t >> 3;
    float a2_[2][4];
#pragma unroll
    for (int i = 0; i < 2; i++)
#pragma unroll
        for (int j = 0; j < 4; j++) a2_[i][j] = sb2[4 * tx2 + j];
#pragma unroll 4
    for (int k = 0; k < 64; k++) {
        const __half2* wp = (const __half2*)&sW2[k * 32 + 4 * tx2];
        float2 wa = __half22float2(wp[0]);
        float2 wb = __half22float2(wp[1]);
        float x0 = sX[(2 * ty2) * XS + k];
        float x1 = sX[(2 * ty2 + 1) * XS + k];
        a2_[0][0] += x0 * wa.x; a2_[0][1] += x0 * wa.y; a2_[0][2] += x0 * wb.x; a2_[0][3] += x0 * wb.y;
        a2_[1][0] += x1 * wa.x; a2_[1][1] += x1 * wa.y; a2_[1][2] += x1 * wb.x; a2_[1][3] += x1 * wb.y;
    }
#pragma unroll
    for (int i = 0; i < 2; i++) {
        float p = fast_tanh(a2_[i][0]) * sW3[4 * tx2]
                + fast_tanh(a2_[i][1]) * sW3[4 * tx2 + 1]
                + fast_tanh(a2_[i][2]) * sW3[4 * tx2 + 2]
                + fast_tanh(a2_[i][3]) * sW3[4 * tx2 + 3];
        sP[(2 * ty2 + i) * 9 + tx2] = p;
    }
    __syncthreads();
    if (t < 64) {
        int n = base + t;
        bool valid = n < 2 * NN;
        int br = n >= NN;
        int g = valid ? (br ? batch_b[n - NN] : batch_a[n]) : -1;
        int key = valid ? (br * 4096 + g) : -1;
        float s0 = sP[t * 9 + 0] + sP[t * 9 + 1] + sP[t * 9 + 2] + sP[t * 9 + 3];
        float s1 = sP[t * 9 + 4] + sP[t * 9 + 5] + sP[t * 9 + 6] + sP[t * 9 + 7];
        sKey[t] = key;
        sVal[t] = s0 + s1 + bb3;
        if (valid && (t == 0 || sKey[t - 1] != key)) {
            float sum = 0.f;
            int cnt = 0;
            for (int j = t; j < 64 && sKey[j] == key; j++) { sum += sVal[j]; cnt++; }
            float* bin = pool + br * 2 * NG;
            atomicAdd(&bin[g], sum);
            atomicAdd(&bin[NG + g], (float)cnt);
        }
    }
}

// pool layout: [sa(NG), ca(NG), sb(NG), cb(NG)]
__global__ void k_final(const float* __restrict__ pool, float* __restrict__ out) {
    int g = blockIdx.x * 256 + threadIdx.x;
    if (g >= NG) return;
    float ua = pool[g] / fmaxf(pool[NG + g], 1.f);
    float ub = pool[2 * NG + g] / fmaxf(pool[3 * NG + g], 1.f);
    float z = ub - ua;
    out[g] = 1.f / (1.f + __expf(-z));
}

extern "C" void kernel_launch(void* const* d_in, const int* in_sizes, int n_in,
                              void* d_out, int out_size, void* d_ws, size_t ws_size,
                              hipStream_t stream) {
    const float* x_a = (const float*)d_in[0];
    const float* x_b = (const float*)d_in[1];
    const int* ei_a = (const int*)d_in[2];
    const int* ei_b = (const int*)d_in[3];
    const int* batch_a = (const int*)d_in[4];
    const int* batch_b = (const int*)d_in[5];
    const float* Wg   = (const float*)d_in[6];
    const float* avs  = (const float*)d_in[7];
    const float* avd  = (const float*)d_in[8];
    const float* bg   = (const float*)d_in[9];
    const float* Wgcn = (const float*)d_in[10];
    const float* bgcn = (const float*)d_in[11];
    const float* W1 = (const float*)d_in[12];
    const float* b1 = (const float*)d_in[13];
    const float* W2 = (const float*)d_in[14];
    const float* b2 = (const float*)d_in[15];
    const float* W3 = (const float*)d_in[16];
    const float* b3 = (const float*)d_in[17];

    char* w = (char*)d_ws;
    __half* A2 = (__half*)w;          w += (size_t)2 * NN * 64 * 2;
    __half* B2 = (__half*)w;          w += (size_t)2 * NN * 64 * 2;
    float* als2 = (float*)w;          w += (size_t)2 * NN * 4;
    float* ald2 = (float*)w;          w += (size_t)2 * NN * 4;
    float* dinv2 = (float*)w;         w += (size_t)2 * NN * 4;
    float* pool = (float*)w;          w += (size_t)4 * NG * 4;
    int* cnt2 = (int*)w;              w += (size_t)2 * NN * 4;
    int* rowptr2 = (int*)w;           w += (size_t)2 * (NN + 1) * 4;
    int* cursor2 = (int*)w;           w += (size_t)2 * NN * 4;
    int* partial = (int*)w;           w += (size_t)2 * NCH * 4;
    u16* csr2 = (u16*)w;

    dim3 blk(256);
    const int gE2 = (2 * NET + 255) / 256;

    hipMemsetAsync(cnt2, 0, 2 * NN * sizeof(int), stream);
    k_deg<<<gE2, blk, 0, stream>>>(ei_a, ei_b, cnt2);
    k_scan1<<<2 * NCH, dim3(512), 0, stream>>>(cnt2, partial);
    k_scan2<<<1, blk, 0, stream>>>(partial, rowptr2, pool);
    k_scan3<<<2 * NCH, dim3(512), 0, stream>>>(cnt2, partial, rowptr2, cursor2, dinv2);
    k_scatter<<<2048, blk, 0, stream>>>(ei_a, ei_b, cursor2, csr2);

    k_gat_input<<<GN4, blk, 0, stream>>>(x_a, x_b, Wg, avs, avd, A2, als2, ald2);
    k_gat_csr<<<GN4, blk, 0, stream>>>(rowptr2, csr2, als2, ald2, A2, bg, B2);
    k_lin_tile<<<NT2, blk, 0, stream>>>(B2, Wgcn, dinv2, A2);
    k_gcn_gather<<<GN4, blk, 0, stream>>>(rowptr2, csr2, dinv2, A2, bgcn, B2);
    k_lin_tile<<<NT2, blk, 0, stream>>>(B2, Wgcn + 64 * 64, dinv2, A2);
    k_gcn_gather<<<GN4, blk, 0, stream>>>(rowptr2, csr2, dinv2, A2, bgcn + 64, B2);
    k_mlp_pool<<<NT2, blk, 0, stream>>>(B2, batch_a, batch_b, W1, b1, W2, b2, W3, b3, pool);

    k_final<<<(NG + 255) / 256, blk, 0, stream>>>(pool, (float*)d_out);
}

// Round 14
// 411.311 us; speedup vs baseline: 1.2679x; 1.2679x over previous
//
#include <hip/hip_runtime.h>
#include <hip/hip_fp16.h>
#include <math.h>

#define NN 50000
#define NE 800000
#define NG 512
#define NET (NE + NN)            // edges + self loops
#define NT2 ((2 * NN + 63) / 64) // 1563 64-node tiles over both branches
#define GN4 ((2 * NN + 3) / 4)   // wave-per-node grids, both branches
#define XS 68                    // node-major LDS stride (x4B: 2-way banks max)

// bucket-sort CSR build
#define SLICE 512                        // dst nodes per slice
#define NSL ((NN + SLICE - 1) / SLICE)   // 98 slices per branch
#define CHK 4096                         // edges per chunk
#define NCK ((NET + CHK - 1) / CHK)      // 208 chunks per branch
#define CAP 10240                        // LDS csr buffer per slice (mean 8704, +16 sigma)

typedef unsigned short u16;

__device__ __forceinline__ float wsum64(float v) {
#pragma unroll
    for (int o = 32; o > 0; o >>= 1) v += __shfl_down(v, o, 64);
    return v;
}

__device__ __forceinline__ float fast_tanh(float x) {
    return 1.f - 2.f / (__expf(2.f * x) + 1.f);
}

// ---------------- CSR build: atomic-free two-level bucket sort ----------------

// Pass 1: per-(branch,chunk) histogram over dst slices (LDS atomics only).
__global__ __launch_bounds__(256) void k_hist(const int* __restrict__ eia,
                                              const int* __restrict__ eib,
                                              int* __restrict__ cnts) {
    __shared__ int h[NSL];
    int b = blockIdx.x;
    int br = b >= NCK, c = b - (br ? NCK : 0);
    int t = threadIdx.x;
    for (int i = t; i < NSL; i += 256) h[i] = 0;
    __syncthreads();
    const int* ei = br ? eib : eia;
    int e0 = c * CHK, e1 = e0 + CHK; if (e1 > NET) e1 = NET;
    for (int e = e0 + t; e < e1; e += 256) {
        int d = (e < NE) ? __builtin_nontemporal_load(&ei[NE + e]) : (e - NE);
        atomicAdd(&h[d >> 9], 1);
    }
    __syncthreads();
    for (int i = t; i < NSL; i += 256) cnts[(br * NSL + i) * NCK + c] = h[i];
}

// Pass 2a: per-slice exclusive scan over its chunk counts (one wave per slice).
__global__ __launch_bounds__(64) void k_off1(int* __restrict__ cnts,
                                             int* __restrict__ sliceBase) {
    int b = blockIdx.x;                  // 2*NSL
    int br = b >= NSL, s = b - (br ? NSL : 0);
    int lane = threadIdx.x;
    int* row = cnts + (br * NSL + s) * NCK;
    int run = 0;
    for (int c0 = 0; c0 < NCK; c0 += 64) {
        int c = c0 + lane;
        int v = (c < NCK) ? row[c] : 0;
        int orig = v;
#pragma unroll
        for (int o = 1; o < 64; o <<= 1) {
            int tv = __shfl_up(v, o, 64);
            if (lane >= o) v += tv;
        }
        if (c < NCK) row[c] = run + v - orig;   // exclusive within slice
        run += __shfl(v, 63, 64);
    }
    if (lane == 0) sliceBase[br * (NSL + 1) + s] = run;  // slice total (scanned in off2)
}

// Pass 2b: scan slice totals -> slice bases; zero pool; rowptr[NN].
__global__ void k_off2(int* __restrict__ sliceBase, int* __restrict__ rowptr2,
                       float* __restrict__ pool) {
    int t = threadIdx.x;  // 256
    for (int i = t; i < 4 * NG; i += 256) pool[i] = 0.f;
    if (t < 2) {
        int* sb = sliceBase + t * (NSL + 1);
        int run = 0;
        for (int s = 0; s < NSL; s++) { int v = sb[s]; sb[s] = run; run += v; }
        sb[NSL] = run;                        // == NET
        rowptr2[t * (NN + 1) + NN] = run;
    }
}

// Pass 3: append edges into slice-segregated staging (LDS cursors, no global atomics).
// staging entry: (dstLocal << 16) | src   (src < 65536, dstLocal < 512)
__global__ __launch_bounds__(256) void k_bucket(const int* __restrict__ eia,
                                                const int* __restrict__ eib,
                                                const int* __restrict__ cnts,
                                                const int* __restrict__ sliceBase,
                                                unsigned int* __restrict__ staging) {
    __shared__ int cur[NSL];
    int b = blockIdx.x;
    int br = b >= NCK, c = b - (br ? NCK : 0);
    int t = threadIdx.x;
    for (int i = t; i < NSL; i += 256)
        cur[i] = cnts[(br * NSL + i) * NCK + c] + sliceBase[br * (NSL + 1) + i];
    __syncthreads();
    const int* ei = br ? eib : eia;
    unsigned int* stg = staging + (size_t)br * NET;
    int e0 = c * CHK, e1 = e0 + CHK; if (e1 > NET) e1 = NET;
    for (int e = e0 + t; e < e1; e += 256) {
        int d, s;
        if (e < NE) {
            d = __builtin_nontemporal_load(&ei[NE + e]);
            s = __builtin_nontemporal_load(&ei[e]);
        } else { d = e - NE; s = d; }
        int pos = atomicAdd(&cur[d >> 9], 1);   // LDS atomic
        stg[pos] = ((unsigned int)(d & 511) << 16) | (unsigned int)s;
    }
}

// Pass 4: per-slice finalize: per-node counts, block scan -> rowptr/dinv,
// place into LDS csr buffer, dump coalesced.
__global__ __launch_bounds__(512) void k_slice(const unsigned int* __restrict__ staging,
                                               const int* __restrict__ sliceBase,
                                               int* __restrict__ rowptr2,
                                               float* __restrict__ dinv2,
                                               u16* __restrict__ csr2) {
    __shared__ int sc[512];
    __shared__ int cur[512];
    __shared__ u16 buf[CAP];
    int b = blockIdx.x;
    int br = b >= NSL, sl = b - (br ? NSL : 0);
    int t = threadIdx.x;
    const int* sb = sliceBase + br * (NSL + 1);
    int base = sb[sl], m = sb[sl + 1] - base;
    const unsigned int* st = staging + (size_t)br * NET + base;
    cur[t] = 0;
    __syncthreads();
    for (int i = t; i < m; i += 512) atomicAdd(&cur[st[i] >> 16], 1);
    __syncthreads();
    int v = cur[t];
    sc[t] = v;
    __syncthreads();
    for (int o = 1; o < 512; o <<= 1) {
        int add = (t >= o) ? sc[t - o] : 0;
        __syncthreads();
        sc[t] += add;
        __syncthreads();
    }
    int excl = sc[t] - v;
    int node = sl * SLICE + t;
    if (node < NN) {
        rowptr2[br * (NN + 1) + node] = base + excl;
        dinv2[br * NN + node] = v > 0 ? rsqrtf((float)v) : 0.f;
    }
    cur[t] = excl;
    __syncthreads();
    for (int i = t; i < m; i += 512) {
        unsigned int e = st[i];
        int pos = atomicAdd(&cur[e >> 16], 1);
        if (pos < CAP) buf[pos] = (u16)(e & 0xffffu);
    }
    __syncthreads();
    u16* out = csr2 + (size_t)br * NET + base;
    int mm = m < CAP ? m : CAP;
    for (int i = t; i < mm; i += 512) out[i] = buf[i];
}

// ---------------- node-level kernels (node id in [0,2*NN)) ----

__global__ void k_gat_input(const float* __restrict__ xa, const float* __restrict__ xb,
                            const float* __restrict__ Wg,
                            const float* __restrict__ avs, const float* __restrict__ avd,
                            __half* __restrict__ A, float* __restrict__ als,
                            float* __restrict__ ald) {
    __shared__ float sW[9 * 64];
    __shared__ float sas[64], sad[64];
    int t = threadIdx.x;
    for (int i = t; i < 9 * 64; i += 256) sW[i] = Wg[i];
    if (t < 64) { sas[t] = avs[t]; sad[t] = avd[t]; }
    __syncthreads();
    int n = blockIdx.x * 4 + (t >> 6);
    int u = t & 63;
    if (n >= 2 * NN) return;
    const float* xp = (n < NN) ? &xa[(size_t)n * 9] : &xb[(size_t)(n - NN) * 9];
    float h = 0.f;
#pragma unroll
    for (int f = 0; f < 9; f++) h += xp[f] * sW[f * 64 + u];
    A[(size_t)n * 64 + u] = __float2half(h);
    float ps = wsum64(h * sas[u]);
    float pd = wsum64(h * sad[u]);
    if (u == 0) { als[n] = ps; ald[n] = pd; }
}

// GAT two-phase: phase A lane-parallel edge weights (1 exp/edge), phase B
// shfl-broadcast + feature-parallel gather-FMA. No max-stab (|e|<~25).
__global__ __launch_bounds__(256) void k_gat_csr(
        const int* __restrict__ rowptr2, const u16* __restrict__ csr2,
        const float* __restrict__ als, const float* __restrict__ ald,
        const __half* __restrict__ A, const float* __restrict__ bias,
        __half* __restrict__ B) {
    int dg = blockIdx.x * 4 + (threadIdx.x >> 6);
    int u = threadIdx.x & 63;
    if (dg >= 2 * NN) return;
    int br = dg >= NN;
    int d = dg - br * NN;
    const int* rp = rowptr2 + br * (NN + 1);
    const u16* cs = csr2 + br * NET;
    int nb = br * NN;
    int beg = rp[d], end = rp[d + 1];
    float ad = ald[dg];
    float acc = 0.f;
    float denl = 0.f;
    for (int c = beg; c < end; c += 64) {
        int idx = c + u;
        int s = 0;
        float w = 0.f;
        if (idx < end) {
            s = nb + cs[idx];
            float v = als[s] + ad;
            w = __expf(fmaxf(v, 0.2f * v));
        }
        denl += w;
        int m = end - c; if (m > 64) m = 64;
        int j = 0;
        for (; j + 4 <= m; j += 4) {
            int s0 = __shfl(s, j, 64),     s1 = __shfl(s, j + 1, 64);
            int s2 = __shfl(s, j + 2, 64), s3 = __shfl(s, j + 3, 64);
            float w0 = __shfl(w, j, 64),     w1 = __shfl(w, j + 1, 64);
            float w2 = __shfl(w, j + 2, 64), w3 = __shfl(w, j + 3, 64);
            float f0 = __half2float(A[(size_t)s0 * 64 + u]);
            float f1 = __half2float(A[(size_t)s1 * 64 + u]);
            float f2 = __half2float(A[(size_t)s2 * 64 + u]);
            float f3 = __half2float(A[(size_t)s3 * 64 + u]);
            acc += f0 * w0 + f1 * w1 + f2 * w2 + f3 * w3;
        }
        for (; j < m; j++) {
            int sj = __shfl(s, j, 64);
            float wj = __shfl(w, j, 64);
            acc += __half2float(A[(size_t)sj * 64 + u]) * wj;
        }
    }
    float den = wsum64(denl);
    den = __shfl(den, 0, 64);
    B[(size_t)dg * 64 + u] = __float2half(fast_tanh(acc / den + bias[u]));
}

// Stage 64-node fp16 tile into LDS node-major: sX[node * XS + feat].
__device__ __forceinline__ void load_tile_NM(const __half* __restrict__ X, int base,
                                             float* sX, int t) {
    const __half2* X2 = (const __half2*)X;
    for (int i = t; i < 2048; i += 256) {
        int node = i >> 5, p = i & 31;
        float2 v;
        if (base + node < 2 * NN) v = __half22float2(X2[(size_t)(base + node) * 32 + p]);
        else v = make_float2(0.f, 0.f);
        *(float2*)&sX[node * XS + 2 * p] = v;
    }
}

// Dense Y = dinv[n] * (X @ W), 64-node tile, 4x4 blocking, fp16 weights/IO.
__global__ __launch_bounds__(256) void k_lin_tile(
        const __half* __restrict__ X, const float* __restrict__ W,
        const float* __restrict__ dinv, __half* __restrict__ Y) {
    __shared__ __half sW[64 * 64];
    __shared__ float sX[64 * XS];
    int t = threadIdx.x;
    for (int i = t; i < 4096; i += 256) sW[i] = __float2half(W[i]);
    int base = blockIdx.x * 64;
    load_tile_NM(X, base, sX, t);
    __syncthreads();
    int tx = t & 15, ty = t >> 4;
    float acc[4][4];
#pragma unroll
    for (int i = 0; i < 4; i++)
#pragma unroll
        for (int j = 0; j < 4; j++) acc[i][j] = 0.f;
#pragma unroll 4
    for (int k = 0; k < 64; k++) {
        const __half2* wp = (const __half2*)&sW[k * 64 + 4 * tx];
        float2 wa = __half22float2(wp[0]);
        float2 wb = __half22float2(wp[1]);
        float x0 = sX[(4 * ty + 0) * XS + k];
        float x1 = sX[(4 * ty + 1) * XS + k];
        float x2 = sX[(4 * ty + 2) * XS + k];
        float x3 = sX[(4 * ty + 3) * XS + k];
        acc[0][0] += x0 * wa.x; acc[0][1] += x0 * wa.y; acc[0][2] += x0 * wb.x; acc[0][3] += x0 * wb.y;
        acc[1][0] += x1 * wa.x; acc[1][1] += x1 * wa.y; acc[1][2] += x1 * wb.x; acc[1][3] += x1 * wb.y;
        acc[2][0] += x2 * wa.x; acc[2][1] += x2 * wa.y; acc[2][2] += x2 * wb.x; acc[2][3] += x2 * wb.y;
        acc[3][0] += x3 * wa.x; acc[3][1] += x3 * wa.y; acc[3][2] += x3 * wb.x; acc[3][3] += x3 * wb.y;
    }
#pragma unroll
    for (int i = 0; i < 4; i++) {
        int n = base + 4 * ty + i;
        if (n < 2 * NN) {
            float dv = dinv[n];
            __half2* Y2 = (__half2*)&Y[(size_t)n * 64 + 4 * tx];
            Y2[0] = __floats2half2_rn(acc[i][0] * dv, acc[i][1] * dv);
            Y2[1] = __floats2half2_rn(acc[i][2] * dv, acc[i][3] * dv);
        }
    }
}

// Lean GCN gather on pre-scaled Y: out = tanh(dinv_d * sum Y[s] + b).
__global__ __launch_bounds__(256) void k_gcn_gather(
        const int* __restrict__ rowptr2, const u16* __restrict__ csr2,
        const float* __restrict__ dinv, const __half* __restrict__ Y,
        const float* __restrict__ bias, __half* __restrict__ Bout) {
    int dg = blockIdx.x * 4 + (threadIdx.x >> 6);
    int u = threadIdx.x & 63;
    if (dg >= 2 * NN) return;
    int br = dg >= NN;
    int d = dg - br * NN;
    const int* rp = rowptr2 + br * (NN + 1);
    const u16* cs = csr2 + br * NET;
    int nb = br * NN;
    int beg = rp[d], end = rp[d + 1];
    float a0 = 0.f, a1 = 0.f, a2 = 0.f, a3 = 0.f;
    for (int c = beg; c < end; c += 64) {
        int idx = c + u;
        int s = (idx < end) ? nb + cs[idx] : 0;   // coalesced
        int m = end - c; if (m > 64) m = 64;
        int j = 0;
        for (; j + 4 <= m; j += 4) {
            int s0 = __shfl(s, j, 64),     s1 = __shfl(s, j + 1, 64);
            int s2 = __shfl(s, j + 2, 64), s3 = __shfl(s, j + 3, 64);
            a0 += __half2float(Y[(size_t)s0 * 64 + u]);
            a1 += __half2float(Y[(size_t)s1 * 64 + u]);
            a2 += __half2float(Y[(size_t)s2 * 64 + u]);
            a3 += __half2float(Y[(size_t)s3 * 64 + u]);
        }
        for (; j < m; j++) {
            int sj = __shfl(s, j, 64);
            a0 += __half2float(Y[(size_t)sj * 64 + u]);
        }
    }
    float h = ((a0 + a1) + (a2 + a3)) * dinv[dg];
    Bout[(size_t)dg * 64 + u] = __float2half(fast_tanh(h + bias[u]));
}

// MLP (64->64 tanh ->32 tanh ->1) + mean-pool. Node-major LDS, fp16 weights,
// segmented-run pool atomics.
__global__ __launch_bounds__(256) void k_mlp_pool(
        const __half* __restrict__ X,
        const int* __restrict__ batch_a, const int* __restrict__ batch_b,
        const float* __restrict__ W1, const float* __restrict__ b1,
        const float* __restrict__ W2, const float* __restrict__ b2,
        const float* __restrict__ W3, const float* __restrict__ b3,
        float* __restrict__ pool) {
    __shared__ __half sW1[64 * 64];
    __shared__ __half sW2[64 * 32];
    __shared__ float sX[64 * XS];
    __shared__ float sP[64 * 9];
    __shared__ float sW3[32], sb1[64], sb2[32];
    __shared__ int sKey[64];
    __shared__ float sVal[64];
    int t = threadIdx.x;
    for (int i = t; i < 4096; i += 256) sW1[i] = __float2half(W1[i]);
    for (int i = t; i < 2048; i += 256) sW2[i] = __float2half(W2[i]);
    if (t < 64) sb1[t] = b1[t];
    if (t < 32) { sW3[t] = W3[t]; sb2[t] = b2[t]; }
    float bb3 = b3[0];
    int base = blockIdx.x * 64;
    load_tile_NM(X, base, sX, t);
    __syncthreads();
    int tx = t & 15, ty = t >> 4;
    float acc[4][4];
#pragma unroll
    for (int i = 0; i < 4; i++)
#pragma unroll
        for (int j = 0; j < 4; j++) acc[i][j] = sb1[4 * tx + j];
#pragma unroll 4
    for (int k = 0; k < 64; k++) {
        const __half2* wp = (const __half2*)&sW1[k * 64 + 4 * tx];
        float2 wa = __half22float2(wp[0]);
        float2 wb = __half22float2(wp[1]);
        float x0 = sX[(4 * ty + 0) * XS + k];
        float x1 = sX[(4 * ty + 1) * XS + k];
        float x2 = sX[(4 * ty + 2) * XS + k];
        float x3 = sX[(4 * ty + 3) * XS + k];
        acc[0][0] += x0 * wa.x; acc[0][1] += x0 * wa.y; acc[0][2] += x0 * wb.x; acc[0][3] += x0 * wb.y;
        acc[1][0] += x1 * wa.x; acc[1][1] += x1 * wa.y; acc[1][2] += x1 * wb.x; acc[1][3] += x1 * wb.y;
        acc[2][0] += x2 * wa.x; acc[2][1] += x2 * wa.y; acc[2][2] += x2 * wb.x; acc[2][3] += x2 * wb.y;
        acc[3][0] += x3 * wa.x; acc[3][1] += x3 * wa.y; acc[3][2] += x3 * wb.x; acc[3][3] += x3 * wb.y;
    }
    __syncthreads();
#pragma unroll
    for (int i = 0; i < 4; i++) {
        float4 o = make_float4(fast_tanh(acc[i][0]), fast_tanh(acc[i][1]),
                               fast_tanh(acc[i][2]), fast_tanh(acc[i][3]));
        *(float4*)&sX[(4 * ty + i) * XS + 4 * tx] = o;
    }
    __syncthreads();
    int tx2 = t & 7, ty2 = t >> 3;
    float a2_[2][4];
#pragma unroll
    for (int i = 0; i < 2; i++)
#pragma unroll
        for (int j = 0; j < 4; j++) a2_[i][j] = sb2[4 * tx2 + j];
#pragma unroll 4
    for (int k = 0; k < 64; k++) {
        const __half2* wp = (const __half2*)&sW2[k * 32 + 4 * tx2];
        float2 wa = __half22float2(wp[0]);
        float2 wb = __half22float2(wp[1]);
        float x0 = sX[(2 * ty2) * XS + k];
        float x1 = sX[(2 * ty2 + 1) * XS + k];
        a2_[0][0] += x0 * wa.x; a2_[0][1] += x0 * wa.y; a2_[0][2] += x0 * wb.x; a2_[0][3] += x0 * wb.y;
        a2_[1][0] += x1 * wa.x; a2_[1][1] += x1 * wa.y; a2_[1][2] += x1 * wb.x; a2_[1][3] += x1 * wb.y;
    }
#pragma unroll
    for (int i = 0; i < 2; i++) {
        float p = fast_tanh(a2_[i][0]) * sW3[4 * tx2]
                + fast_tanh(a2_[i][1]) * sW3[4 * tx2 + 1]
                + fast_tanh(a2_[i][2]) * sW3[4 * tx2 + 2]
                + fast_tanh(a2_[i][3]) * sW3[4 * tx2 + 3];
        sP[(2 * ty2 + i) * 9 + tx2] = p;
    }
    __syncthreads();
    if (t < 64) {
        int n = base + t;
        bool valid = n < 2 * NN;
        int br = n >= NN;
        int g = valid ? (br ? batch_b[n - NN] : batch_a[n]) : -1;
        int key = valid ? (br * 4096 + g) : -1;
        float s0 = sP[t * 9 + 0] + sP[t * 9 + 1] + sP[t * 9 + 2] + sP[t * 9 + 3];
        float s1 = sP[t * 9 + 4] + sP[t * 9 + 5] + sP[t * 9 + 6] + sP[t * 9 + 7];
        sKey[t] = key;
        sVal[t] = s0 + s1 + bb3;
        if (valid && (t == 0 || sKey[t - 1] != key)) {
            float sum = 0.f;
            int cnt = 0;
            for (int j = t; j < 64 && sKey[j] == key; j++) { sum += sVal[j]; cnt++; }
            float* bin = pool + br * 2 * NG;
            atomicAdd(&bin[g], sum);
            atomicAdd(&bin[NG + g], (float)cnt);
        }
    }
}

// pool layout: [sa(NG), ca(NG), sb(NG), cb(NG)]
__global__ void k_final(const float* __restrict__ pool, float* __restrict__ out) {
    int g = blockIdx.x * 256 + threadIdx.x;
    if (g >= NG) return;
    float ua = pool[g] / fmaxf(pool[NG + g], 1.f);
    float ub = pool[2 * NG + g] / fmaxf(pool[3 * NG + g], 1.f);
    float z = ub - ua;
    out[g] = 1.f / (1.f + __expf(-z));
}

extern "C" void kernel_launch(void* const* d_in, const int* in_sizes, int n_in,
                              void* d_out, int out_size, void* d_ws, size_t ws_size,
                              hipStream_t stream) {
    const float* x_a = (const float*)d_in[0];
    const float* x_b = (const float*)d_in[1];
    const int* ei_a = (const int*)d_in[2];
    const int* ei_b = (const int*)d_in[3];
    const int* batch_a = (const int*)d_in[4];
    const int* batch_b = (const int*)d_in[5];
    const float* Wg   = (const float*)d_in[6];
    const float* avs  = (const float*)d_in[7];
    const float* avd  = (const float*)d_in[8];
    const float* bg   = (const float*)d_in[9];
    const float* Wgcn = (const float*)d_in[10];
    const float* bgcn = (const float*)d_in[11];
    const float* W1 = (const float*)d_in[12];
    const float* b1 = (const float*)d_in[13];
    const float* W2 = (const float*)d_in[14];
    const float* b2 = (const float*)d_in[15];
    const float* W3 = (const float*)d_in[16];
    const float* b3 = (const float*)d_in[17];

    char* w = (char*)d_ws;
    __half* A2 = (__half*)w;          w += (size_t)2 * NN * 64 * 2;   // 12.8 MB
    __half* B2 = (__half*)w;          w += (size_t)2 * NN * 64 * 2;   // 12.8 MB
    float* als2 = (float*)w;          w += (size_t)2 * NN * 4;
    float* ald2 = (float*)w;          w += (size_t)2 * NN * 4;
    float* dinv2 = (float*)w;         w += (size_t)2 * NN * 4;
    float* pool = (float*)w;          w += (size_t)4 * NG * 4;
    int* rowptr2 = (int*)w;           w += (size_t)2 * (NN + 1) * 4;
    int* cnts = (int*)w;              w += (size_t)2 * NSL * NCK * 4; // 163 KB
    int* sliceBase = (int*)w;         w += (size_t)2 * (NSL + 1) * 4;
    u16* csr2 = (u16*)w;
    // staging (2*NET u32 = 6.8 MB) aliases A2: dead before k_gat_input writes A2
    unsigned int* staging = (unsigned int*)A2;

    dim3 blk(256);

    // CSR build: atomic-free bucket sort
    k_hist<<<2 * NCK, blk, 0, stream>>>(ei_a, ei_b, cnts);
    k_off1<<<2 * NSL, dim3(64), 0, stream>>>(cnts, sliceBase);
    k_off2<<<1, blk, 0, stream>>>(sliceBase, rowptr2, pool);
    k_bucket<<<2 * NCK, blk, 0, stream>>>(ei_a, ei_b, cnts, sliceBase, staging);
    k_slice<<<2 * NSL, dim3(512), 0, stream>>>(staging, sliceBase, rowptr2, dinv2, csr2);

    k_gat_input<<<GN4, blk, 0, stream>>>(x_a, x_b, Wg, avs, avd, A2, als2, ald2);
    k_gat_csr<<<GN4, blk, 0, stream>>>(rowptr2, csr2, als2, ald2, A2, bg, B2);
    k_lin_tile<<<NT2, blk, 0, stream>>>(B2, Wgcn, dinv2, A2);
    k_gcn_gather<<<GN4, blk, 0, stream>>>(rowptr2, csr2, dinv2, A2, bgcn, B2);
    k_lin_tile<<<NT2, blk, 0, stream>>>(B2, Wgcn + 64 * 64, dinv2, A2);
    k_gcn_gather<<<GN4, blk, 0, stream>>>(rowptr2, csr2, dinv2, A2, bgcn + 64, B2);
    k_mlp_pool<<<NT2, blk, 0, stream>>>(B2, batch_a, batch_b, W1, b1, W2, b2, W3, b3, pool);

    k_final<<<(NG + 255) / 256, blk, 0, stream>>>(pool, (float*)d_out);
}

// Round 15
// 380.046 us; speedup vs baseline: 1.3722x; 1.0823x over previous
//
#include <hip/hip_runtime.h>
#include <hip/hip_fp16.h>
#include <math.h>

#define NN 50000
#define NE 800000
#define NG 512
#define NET (NE + NN)            // edges + self loops
#define NT2 ((2 * NN + 63) / 64) // 1563 64-node tiles over both branches
#define GN4 ((2 * NN + 3) / 4)   // wave-per-node grids
#define GN8 ((2 * NN + 7) / 8)   // 2-dst-per-wave gather grids
#define XS 68                    // node-major LDS stride (x4B: 2-way banks max)

// bucket-sort CSR build
#define SLICE 512                        // dst nodes per slice
#define NSL ((NN + SLICE - 1) / SLICE)   // 98 slices per branch
#define CHK 4096                         // edges per chunk
#define NCK ((NET + CHK - 1) / CHK)      // 208 chunks per branch
#define CAP 10240                        // LDS csr buffer per slice

typedef unsigned short u16;

__device__ __forceinline__ float wsum64(float v) {
#pragma unroll
    for (int o = 32; o > 0; o >>= 1) v += __shfl_down(v, o, 64);
    return v;
}

__device__ __forceinline__ float fast_tanh(float x) {
    return 1.f - 2.f / (__expf(2.f * x) + 1.f);
}

// ---------------- CSR build: atomic-free two-level bucket sort ----------------

__global__ __launch_bounds__(256) void k_hist(const int* __restrict__ eia,
                                              const int* __restrict__ eib,
                                              int* __restrict__ cnts) {
    __shared__ int h[NSL];
    int b = blockIdx.x;
    int br = b >= NCK, c = b - (br ? NCK : 0);
    int t = threadIdx.x;
    for (int i = t; i < NSL; i += 256) h[i] = 0;
    __syncthreads();
    const int* ei = br ? eib : eia;
    int e0 = c * CHK, e1 = e0 + CHK; if (e1 > NET) e1 = NET;
    for (int e = e0 + t; e < e1; e += 256) {
        int d = (e < NE) ? __builtin_nontemporal_load(&ei[NE + e]) : (e - NE);
        atomicAdd(&h[d >> 9], 1);
    }
    __syncthreads();
    for (int i = t; i < NSL; i += 256) cnts[(br * NSL + i) * NCK + c] = h[i];
}

__global__ __launch_bounds__(64) void k_off1(int* __restrict__ cnts,
                                             int* __restrict__ sliceBase) {
    int b = blockIdx.x;                  // 2*NSL
    int br = b >= NSL, s = b - (br ? NSL : 0);
    int lane = threadIdx.x;
    int* row = cnts + (br * NSL + s) * NCK;
    int run = 0;
    for (int c0 = 0; c0 < NCK; c0 += 64) {
        int c = c0 + lane;
        int v = (c < NCK) ? row[c] : 0;
        int orig = v;
#pragma unroll
        for (int o = 1; o < 64; o <<= 1) {
            int tv = __shfl_up(v, o, 64);
            if (lane >= o) v += tv;
        }
        if (c < NCK) row[c] = run + v - orig;
        run += __shfl(v, 63, 64);
    }
    if (lane == 0) sliceBase[br * (NSL + 1) + s] = run;
}

__global__ void k_off2(int* __restrict__ sliceBase, int* __restrict__ rowptr2,
                       float* __restrict__ pool) {
    int t = threadIdx.x;  // 256
    for (int i = t; i < 4 * NG; i += 256) pool[i] = 0.f;
    if (t < 2) {
        int* sb = sliceBase + t * (NSL + 1);
        int run = 0;
        for (int s = 0; s < NSL; s++) { int v = sb[s]; sb[s] = run; run += v; }
        sb[NSL] = run;
        rowptr2[t * (NN + 1) + NN] = run;
    }
}

__global__ __launch_bounds__(256) void k_bucket(const int* __restrict__ eia,
                                                const int* __restrict__ eib,
                                                const int* __restrict__ cnts,
                                                const int* __restrict__ sliceBase,
                                                unsigned int* __restrict__ staging) {
    __shared__ int cur[NSL];
    int b = blockIdx.x;
    int br = b >= NCK, c = b - (br ? NCK : 0);
    int t = threadIdx.x;
    for (int i = t; i < NSL; i += 256)
        cur[i] = cnts[(br * NSL + i) * NCK + c] + sliceBase[br * (NSL + 1) + i];
    __syncthreads();
    const int* ei = br ? eib : eia;
    unsigned int* stg = staging + (size_t)br * NET;
    int e0 = c * CHK, e1 = e0 + CHK; if (e1 > NET) e1 = NET;
    for (int e = e0 + t; e < e1; e += 256) {
        int d, s;
        if (e < NE) {
            d = __builtin_nontemporal_load(&ei[NE + e]);
            s = __builtin_nontemporal_load(&ei[e]);
        } else { d = e - NE; s = d; }
        int pos = atomicAdd(&cur[d >> 9], 1);   // LDS atomic
        stg[pos] = ((unsigned int)(d & 511) << 16) | (unsigned int)s;
    }
}

__global__ __launch_bounds__(512) void k_slice(const unsigned int* __restrict__ staging,
                                               const int* __restrict__ sliceBase,
                                               int* __restrict__ rowptr2,
                                               float* __restrict__ dinv2,
                                               u16* __restrict__ csr2) {
    __shared__ int sc[512];
    __shared__ int cur[512];
    __shared__ u16 buf[CAP];
    int b = blockIdx.x;
    int br = b >= NSL, sl = b - (br ? NSL : 0);
    int t = threadIdx.x;
    const int* sb = sliceBase + br * (NSL + 1);
    int base = sb[sl], m = sb[sl + 1] - base;
    const unsigned int* st = staging + (size_t)br * NET + base;
    cur[t] = 0;
    __syncthreads();
    for (int i = t; i < m; i += 512) atomicAdd(&cur[st[i] >> 16], 1);
    __syncthreads();
    int v = cur[t];
    sc[t] = v;
    __syncthreads();
    for (int o = 1; o < 512; o <<= 1) {
        int add = (t >= o) ? sc[t - o] : 0;
        __syncthreads();
        sc[t] += add;
        __syncthreads();
    }
    int excl = sc[t] - v;
    int node = sl * SLICE + t;
    if (node < NN) {
        rowptr2[br * (NN + 1) + node] = base + excl;
        dinv2[br * NN + node] = v > 0 ? rsqrtf((float)v) : 0.f;
    }
    cur[t] = excl;
    __syncthreads();
    for (int i = t; i < m; i += 512) {
        unsigned int e = st[i];
        int pos = atomicAdd(&cur[e >> 16], 1);
        if (pos < CAP) buf[pos] = (u16)(e & 0xffffu);
    }
    __syncthreads();
    u16* out = csr2 + (size_t)br * NET + base;
    int mm = m < CAP ? m : CAP;
    for (int i = t; i < mm; i += 512) out[i] = buf[i];
}

// ---------------- node-level kernels (node id in [0,2*NN)) ----

__global__ void k_gat_input(const float* __restrict__ xa, const float* __restrict__ xb,
                            const float* __restrict__ Wg,
                            const float* __restrict__ avs, const float* __restrict__ avd,
                            __half* __restrict__ A, float* __restrict__ als,
                            float* __restrict__ ald) {
    __shared__ float sW[9 * 64];
    __shared__ float sas[64], sad[64];
    int t = threadIdx.x;
    for (int i = t; i < 9 * 64; i += 256) sW[i] = Wg[i];
    if (t < 64) { sas[t] = avs[t]; sad[t] = avd[t]; }
    __syncthreads();
    int n = blockIdx.x * 4 + (t >> 6);
    int u = t & 63;
    if (n >= 2 * NN) return;
    const float* xp = (n < NN) ? &xa[(size_t)n * 9] : &xb[(size_t)(n - NN) * 9];
    float h = 0.f;
#pragma unroll
    for (int f = 0; f < 9; f++) h += xp[f] * sW[f * 64 + u];
    A[(size_t)n * 64 + u] = __float2half(h);
    float ps = wsum64(h * sas[u]);
    float pd = wsum64(h * sad[u]);
    if (u == 0) { als[n] = ps; ald[n] = pd; }
}

// GAT gather, 2 dsts per wave: lanes 0-31 -> dst0 (feats as half2), 32-63 -> dst1.
// Each wave retires 2 edges per inner step (one per half). Phase A: 32-edge
// chunks, lane-parallel weights (1 exp/edge). Phase B: bpermute-broadcast (s,w),
// half2 gather-FMA. No max-stab (|e|<~25, fp32-safe).
__global__ __launch_bounds__(256) void k_gat_csr(
        const int* __restrict__ rowptr2, const u16* __restrict__ csr2,
        const float* __restrict__ als, const float* __restrict__ ald,
        const __half* __restrict__ A, const float* __restrict__ bias,
        __half* __restrict__ B) {
    int u = threadIdx.x & 63;
    int half = u >> 5, lu = u & 31;
    int dg = blockIdx.x * 8 + (threadIdx.x >> 6) * 2 + half;
    if (dg >= 2 * NN) return;
    int br = dg >= NN;
    int d = dg - br * NN;
    const int* rp = rowptr2 + br * (NN + 1);
    const u16* cs = csr2 + br * NET;
    int nb = br * NN;
    int beg = rp[d], end = rp[d + 1];
    float ad = ald[dg];
    const __half2* Ap = (const __half2*)A;
    float ax0 = 0.f, ay0 = 0.f, ax1 = 0.f, ay1 = 0.f;
    float denl = 0.f;
    int baseLane = half << 5;
    for (int c = beg; c < end; c += 32) {
        int idx = c + lu;
        int s = 0;
        float w = 0.f;
        if (idx < end) {
            s = nb + cs[idx];                 // coalesced within half
            float v = als[s] + ad;
            w = __expf(fmaxf(v, 0.2f * v));
        }
        denl += w;
        int m = end - c; if (m > 32) m = 32;
        int j = 0;
        for (; j + 2 <= m; j += 2) {
            int s0 = __shfl(s, baseLane + j, 64);
            int s1 = __shfl(s, baseLane + j + 1, 64);
            float w0 = __shfl(w, baseLane + j, 64);
            float w1 = __shfl(w, baseLane + j + 1, 64);
            float2 f0 = __half22float2(Ap[(size_t)s0 * 32 + lu]);
            float2 f1 = __half22float2(Ap[(size_t)s1 * 32 + lu]);
            ax0 += f0.x * w0; ay0 += f0.y * w0;
            ax1 += f1.x * w1; ay1 += f1.y * w1;
        }
        for (; j < m; j++) {
            int sj = __shfl(s, baseLane + j, 64);
            float wj = __shfl(w, baseLane + j, 64);
            float2 f = __half22float2(Ap[(size_t)sj * 32 + lu]);
            ax0 += f.x * wj; ay0 += f.y * wj;
        }
    }
    float den = denl;
#pragma unroll
    for (int o = 16; o > 0; o >>= 1) den += __shfl_down(den, o, 32);
    den = __shfl(den, 0, 32);
    float inv = 1.f / den;
    float2 bb = *(const float2*)&bias[2 * lu];
    ((__half2*)B)[(size_t)dg * 32 + lu] =
        __floats2half2_rn(fast_tanh((ax0 + ax1) * inv + bb.x),
                          fast_tanh((ay0 + ay1) * inv + bb.y));
}

// Stage 64-node fp16 tile into LDS node-major: sX[node * XS + feat].
__device__ __forceinline__ void load_tile_NM(const __half* __restrict__ X, int base,
                                             float* sX, int t) {
    const __half2* X2 = (const __half2*)X;
    for (int i = t; i < 2048; i += 256) {
        int node = i >> 5, p = i & 31;
        float2 v;
        if (base + node < 2 * NN) v = __half22float2(X2[(size_t)(base + node) * 32 + p]);
        else v = make_float2(0.f, 0.f);
        *(float2*)&sX[node * XS + 2 * p] = v;
    }
}

// Dense Y = dinv[n] * (X @ W), 64-node tile, 4x4 blocking, fp16 weights/IO.
__global__ __launch_bounds__(256) void k_lin_tile(
        const __half* __restrict__ X, const float* __restrict__ W,
        const float* __restrict__ dinv, __half* __restrict__ Y) {
    __shared__ __half sW[64 * 64];
    __shared__ float sX[64 * XS];
    int t = threadIdx.x;
    for (int i = t; i < 4096; i += 256) sW[i] = __float2half(W[i]);
    int base = blockIdx.x * 64;
    load_tile_NM(X, base, sX, t);
    __syncthreads();
    int tx = t & 15, ty = t >> 4;
    float acc[4][4];
#pragma unroll
    for (int i = 0; i < 4; i++)
#pragma unroll
        for (int j = 0; j < 4; j++) acc[i][j] = 0.f;
#pragma unroll 4
    for (int k = 0; k < 64; k++) {
        const __half2* wp = (const __half2*)&sW[k * 64 + 4 * tx];
        float2 wa = __half22float2(wp[0]);
        float2 wb = __half22float2(wp[1]);
        float x0 = sX[(4 * ty + 0) * XS + k];
        float x1 = sX[(4 * ty + 1) * XS + k];
        float x2 = sX[(4 * ty + 2) * XS + k];
        float x3 = sX[(4 * ty + 3) * XS + k];
        acc[0][0] += x0 * wa.x; acc[0][1] += x0 * wa.y; acc[0][2] += x0 * wb.x; acc[0][3] += x0 * wb.y;
        acc[1][0] += x1 * wa.x; acc[1][1] += x1 * wa.y; acc[1][2] += x1 * wb.x; acc[1][3] += x1 * wb.y;
        acc[2][0] += x2 * wa.x; acc[2][1] += x2 * wa.y; acc[2][2] += x2 * wb.x; acc[2][3] += x2 * wb.y;
        acc[3][0] += x3 * wa.x; acc[3][1] += x3 * wa.y; acc[3][2] += x3 * wb.x; acc[3][3] += x3 * wb.y;
    }
#pragma unroll
    for (int i = 0; i < 4; i++) {
        int n = base + 4 * ty + i;
        if (n < 2 * NN) {
            float dv = dinv[n];
            __half2* Y2 = (__half2*)&Y[(size_t)n * 64 + 4 * tx];
            Y2[0] = __floats2half2_rn(acc[i][0] * dv, acc[i][1] * dv);
            Y2[1] = __floats2half2_rn(acc[i][2] * dv, acc[i][3] * dv);
        }
    }
}

// GCN gather on pre-scaled Y, 2 dsts per wave (half2 features).
__global__ __launch_bounds__(256) void k_gcn_gather(
        const int* __restrict__ rowptr2, const u16* __restrict__ csr2,
        const float* __restrict__ dinv, const __half* __restrict__ Y,
        const float* __restrict__ bias, __half* __restrict__ Bout) {
    int u = threadIdx.x & 63;
    int half = u >> 5, lu = u & 31;
    int dg = blockIdx.x * 8 + (threadIdx.x >> 6) * 2 + half;
    if (dg >= 2 * NN) return;
    int br = dg >= NN;
    int d = dg - br * NN;
    const int* rp = rowptr2 + br * (NN + 1);
    const u16* cs = csr2 + br * NET;
    int nb = br * NN;
    int beg = rp[d], end = rp[d + 1];
    const __half2* Yp = (const __half2*)Y;
    float ax0 = 0.f, ay0 = 0.f, ax1 = 0.f, ay1 = 0.f;
    int baseLane = half << 5;
    for (int c = beg; c < end; c += 32) {
        int idx = c + lu;
        int s = (idx < end) ? nb + cs[idx] : 0;
        int m = end - c; if (m > 32) m = 32;
        int j = 0;
        for (; j + 2 <= m; j += 2) {
            int s0 = __shfl(s, baseLane + j, 64);
            int s1 = __shfl(s, baseLane + j + 1, 64);
            float2 f0 = __half22float2(Yp[(size_t)s0 * 32 + lu]);
            float2 f1 = __half22float2(Yp[(size_t)s1 * 32 + lu]);
            ax0 += f0.x; ay0 += f0.y;
            ax1 += f1.x; ay1 += f1.y;
        }
        for (; j < m; j++) {
            int sj = __shfl(s, baseLane + j, 64);
            float2 f = __half22float2(Yp[(size_t)sj * 32 + lu]);
            ax0 += f.x; ay0 += f.y;
        }
    }
    float dv = dinv[dg];
    float2 bb = *(const float2*)&bias[2 * lu];
    ((__half2*)Bout)[(size_t)dg * 32 + lu] =
        __floats2half2_rn(fast_tanh((ax0 + ax1) * dv + bb.x),
                          fast_tanh((ay0 + ay1) * dv + bb.y));
}

// MLP (64->64 tanh ->32 tanh ->1) + mean-pool. Node-major LDS, fp16 weights,
// segmented-run pool atomics.
__global__ __launch_bounds__(256) void k_mlp_pool(
        const __half* __restrict__ X,
        const int* __restrict__ batch_a, const int* __restrict__ batch_b,
        const float* __restrict__ W1, const float* __restrict__ b1,
        const float* __restrict__ W2, const float* __restrict__ b2,
        const float* __restrict__ W3, const float* __restrict__ b3,
        float* __restrict__ pool) {
    __shared__ __half sW1[64 * 64];
    __shared__ __half sW2[64 * 32];
    __shared__ float sX[64 * XS];
    __shared__ float sP[64 * 9];
    __shared__ float sW3[32], sb1[64], sb2[32];
    __shared__ int sKey[64];
    __shared__ float sVal[64];
    int t = threadIdx.x;
    for (int i = t; i < 4096; i += 256) sW1[i] = __float2half(W1[i]);
    for (int i = t; i < 2048; i += 256) sW2[i] = __float2half(W2[i]);
    if (t < 64) sb1[t] = b1[t];
    if (t < 32) { sW3[t] = W3[t]; sb2[t] = b2[t]; }
    float bb3 = b3[0];
    int base = blockIdx.x * 64;
    load_tile_NM(X, base, sX, t);
    __syncthreads();
    int tx = t & 15, ty = t >> 4;
    float acc[4][4];
#pragma unroll
    for (int i = 0; i < 4; i++)
#pragma unroll
        for (int j = 0; j < 4; j++) acc[i][j] = sb1[4 * tx + j];
#pragma unroll 4
    for (int k = 0; k < 64; k++) {
        const __half2* wp = (const __half2*)&sW1[k * 64 + 4 * tx];
        float2 wa = __half22float2(wp[0]);
        float2 wb = __half22float2(wp[1]);
        float x0 = sX[(4 * ty + 0) * XS + k];
        float x1 = sX[(4 * ty + 1) * XS + k];
        float x2 = sX[(4 * ty + 2) * XS + k];
        float x3 = sX[(4 * ty + 3) * XS + k];
        acc[0][0] += x0 * wa.x; acc[0][1] += x0 * wa.y; acc[0][2] += x0 * wb.x; acc[0][3] += x0 * wb.y;
        acc[1][0] += x1 * wa.x; acc[1][1] += x1 * wa.y; acc[1][2] += x1 * wb.x; acc[1][3] += x1 * wb.y;
        acc[2][0] += x2 * wa.x; acc[2][1] += x2 * wa.y; acc[2][2] += x2 * wb.x; acc[2][3] += x2 * wb.y;
        acc[3][0] += x3 * wa.x; acc[3][1] += x3 * wa.y; acc[3][2] += x3 * wb.x; acc[3][3] += x3 * wb.y;
    }
    __syncthreads();
#pragma unroll
    for (int i = 0; i < 4; i++) {
        float4 o = make_float4(fast_tanh(acc[i][0]), fast_tanh(acc[i][1]),
                               fast_tanh(acc[i][2]), fast_tanh(acc[i][3]));
        *(float4*)&sX[(4 * ty + i) * XS + 4 * tx] = o;
    }
    __syncthreads();
    int tx2 = t & 7, ty2 = t >> 3;
    float a2_[2][4];
#pragma unroll
    for (int i = 0; i < 2; i++)
#pragma unroll
        for (int j = 0; j < 4; j++) a2_[i][j] = sb2[4 * tx2 + j];
#pragma unroll 4
    for (int k = 0; k < 64; k++) {
        const __half2* wp = (const __half2*)&sW2[k * 32 + 4 * tx2];
        float2 wa = __half22float2(wp[0]);
        float2 wb = __half22float2(wp[1]);
        float x0 = sX[(2 * ty2) * XS + k];
        float x1 = sX[(2 * ty2 + 1) * XS + k];
        a2_[0][0] += x0 * wa.x; a2_[0][1] += x0 * wa.y; a2_[0][2] += x0 * wb.x; a2_[0][3] += x0 * wb.y;
        a2_[1][0] += x1 * wa.x; a2_[1][1] += x1 * wa.y; a2_[1][2] += x1 * wb.x; a2_[1][3] += x1 * wb.y;
    }
#pragma unroll
    for (int i = 0; i < 2; i++) {
        float p = fast_tanh(a2_[i][0]) * sW3[4 * tx2]
                + fast_tanh(a2_[i][1]) * sW3[4 * tx2 + 1]
                + fast_tanh(a2_[i][2]) * sW3[4 * tx2 + 2]
                + fast_tanh(a2_[i][3]) * sW3[4 * tx2 + 3];
        sP[(2 * ty2 + i) * 9 + tx2] = p;
    }
    __syncthreads();
    if (t < 64) {
        int n = base + t;
        bool valid = n < 2 * NN;
        int br = n >= NN;
        int g = valid ? (br ? batch_b[n - NN] : batch_a[n]) : -1;
        int key = valid ? (br * 4096 + g) : -1;
        float s0 = sP[t * 9 + 0] + sP[t * 9 + 1] + sP[t * 9 + 2] + sP[t * 9 + 3];
        float s1 = sP[t * 9 + 4] + sP[t * 9 + 5] + sP[t * 9 + 6] + sP[t * 9 + 7];
        sKey[t] = key;
        sVal[t] = s0 + s1 + bb3;
        if (valid && (t == 0 || sKey[t - 1] != key)) {
            float sum = 0.f;
            int cnt = 0;
            for (int j = t; j < 64 && sKey[j] == key; j++) { sum += sVal[j]; cnt++; }
            float* bin = pool + br * 2 * NG;
            atomicAdd(&bin[g], sum);
            atomicAdd(&bin[NG + g], (float)cnt);
        }
    }
}

// pool layout: [sa(NG), ca(NG), sb(NG), cb(NG)]
__global__ void k_final(const float* __restrict__ pool, float* __restrict__ out) {
    int g = blockIdx.x * 256 + threadIdx.x;
    if (g >= NG) return;
    float ua = pool[g] / fmaxf(pool[NG + g], 1.f);
    float ub = pool[2 * NG + g] / fmaxf(pool[3 * NG + g], 1.f);
    float z = ub - ua;
    out[g] = 1.f / (1.f + __expf(-z));
}

extern "C" void kernel_launch(void* const* d_in, const int* in_sizes, int n_in,
                              void* d_out, int out_size, void* d_ws, size_t ws_size,
                              hipStream_t stream) {
    const float* x_a = (const float*)d_in[0];
    const float* x_b = (const float*)d_in[1];
    const int* ei_a = (const int*)d_in[2];
    const int* ei_b = (const int*)d_in[3];
    const int* batch_a = (const int*)d_in[4];
    const int* batch_b = (const int*)d_in[5];
    const float* Wg   = (const float*)d_in[6];
    const float* avs  = (const float*)d_in[7];
    const float* avd  = (const float*)d_in[8];
    const float* bg   = (const float*)d_in[9];
    const float* Wgcn = (const float*)d_in[10];
    const float* bgcn = (const float*)d_in[11];
    const float* W1 = (const float*)d_in[12];
    const float* b1 = (const float*)d_in[13];
    const float* W2 = (const float*)d_in[14];
    const float* b2 = (const float*)d_in[15];
    const float* W3 = (const float*)d_in[16];
    const float* b3 = (const float*)d_in[17];

    char* w = (char*)d_ws;
    __half* A2 = (__half*)w;          w += (size_t)2 * NN * 64 * 2;   // 12.8 MB
    __half* B2 = (__half*)w;          w += (size_t)2 * NN * 64 * 2;   // 12.8 MB
    float* als2 = (float*)w;          w += (size_t)2 * NN * 4;
    float* ald2 = (float*)w;          w += (size_t)2 * NN * 4;
    float* dinv2 = (float*)w;         w += (size_t)2 * NN * 4;
    float* pool = (float*)w;          w += (size_t)4 * NG * 4;
    int* rowptr2 = (int*)w;           w += (size_t)2 * (NN + 1) * 4;
    int* cnts = (int*)w;              w += (size_t)2 * NSL * NCK * 4; // 163 KB
    int* sliceBase = (int*)w;         w += (size_t)2 * (NSL + 1) * 4;
    u16* csr2 = (u16*)w;
    // staging (2*NET u32 = 6.8 MB) aliases A2: dead before k_gat_input writes A2
    unsigned int* staging = (unsigned int*)A2;

    dim3 blk(256);

    // CSR build: atomic-free bucket sort
    k_hist<<<2 * NCK, blk, 0, stream>>>(ei_a, ei_b, cnts);
    k_off1<<<2 * NSL, dim3(64), 0, stream>>>(cnts, sliceBase);
    k_off2<<<1, blk, 0, stream>>>(sliceBase, rowptr2, pool);
    k_bucket<<<2 * NCK, blk, 0, stream>>>(ei_a, ei_b, cnts, sliceBase, staging);
    k_slice<<<2 * NSL, dim3(512), 0, stream>>>(staging, sliceBase, rowptr2, dinv2, csr2);

    k_gat_input<<<GN4, blk, 0, stream>>>(x_a, x_b, Wg, avs, avd, A2, als2, ald2);
    k_gat_csr<<<GN8, blk, 0, stream>>>(rowptr2, csr2, als2, ald2, A2, bg, B2);
    k_lin_tile<<<NT2, blk, 0, stream>>>(B2, Wgcn, dinv2, A2);
    k_gcn_gather<<<GN8, blk, 0, stream>>>(rowptr2, csr2, dinv2, A2, bgcn, B2);
    k_lin_tile<<<NT2, blk, 0, stream>>>(B2, Wgcn + 64 * 64, dinv2, A2);
    k_gcn_gather<<<GN8, blk, 0, stream>>>(rowptr2, csr2, dinv2, A2, bgcn + 64, B2);
    k_mlp_pool<<<NT2, blk, 0, stream>>>(B2, batch_a, batch_b, W1, b1, W2, b2, W3, b3, pool);

    k_final<<<(NG + 255) / 256, blk, 0, stream>>>(pool, (float*)d_out);
}